// Round 1
// baseline (82.482 us; speedup 1.0000x reference)
//
#include <hip/hip_runtime.h>

#define B_ 8
#define C_ 2048
#define T_ 2048
#define NT_ 2048

typedef float v4 __attribute__((ext_vector_type(4)));

// ---------------- kernel 1: global min/max over xc and xt ----------------
__global__ __launch_bounds__(256) void k_minmax(const float* __restrict__ xc,
                                                const float* __restrict__ xt,
                                                float* __restrict__ ws) {
    __shared__ float slo[256], shi[256];
    int t = threadIdx.x;
    float lo = 1e30f, hi = -1e30f;
    for (int idx = t; idx < B_ * C_; idx += 256) {
        float a = xc[idx];
        lo = fminf(lo, a); hi = fmaxf(hi, a);
        float c = xt[idx];
        lo = fminf(lo, c); hi = fmaxf(hi, c);
    }
    slo[t] = lo; shi[t] = hi;
    __syncthreads();
    for (int s = 128; s > 0; s >>= 1) {
        if (t < s) {
            slo[t] = fminf(slo[t], slo[t + s]);
            shi[t] = fmaxf(shi[t], shi[t + s]);
        }
        __syncthreads();
    }
    if (t == 0) {
        float lower = slo[0], upper = shi[0];
        ws[0] = lower;
        ws[1] = (upper - lower) * (1.0f / 2047.0f);  // linspace step
    }
}

// ---------------- kernel 2: SetConv (Ktc @ [1,y]) + MLP -> act0 (B,8,NT) ----------------
__global__ __launch_bounds__(256) void k_stageA(const float* __restrict__ xc,
                                                const float* __restrict__ yc,
                                                const float* __restrict__ psi_ls,
                                                const float* __restrict__ psi_os,
                                                const float* __restrict__ mlp_w,
                                                const float* __restrict__ mlp_b,
                                                const float* __restrict__ ws,
                                                float* __restrict__ act0) {
    __shared__ float2 cxy[C_];
    __shared__ float2 red[256];
    int t = threadIdx.x;
    int b = blockIdx.y;
    int o0 = blockIdx.x * 64;
    const float* xcb = xc + b * C_;
    const float* ycb = yc + b * C_;
    for (int j = t; j < C_; j += 256) cxy[j] = make_float2(xcb[j], ycb[j]);
    __syncthreads();

    float lower = ws[0], step = ws[1];
    float ls = psi_ls[0], os = psi_os[0];
    float nh = -0.5f / (ls * ls);

    int il = t & 63, g = t >> 6;
    int i = o0 + il;
    float ti = lower + step * (float)i;
    float h0 = 0.f, h1 = 0.f;
    int jb = g * 512;
    #pragma unroll 4
    for (int jj = 0; jj < 512; ++jj) {
        float2 p = cxy[jb + jj];       // wave-uniform address -> LDS broadcast
        float d = ti - p.x;
        float e = __expf(nh * d * d);
        h0 += e;
        h1 += e * p.y;
    }
    red[t] = make_float2(h0, h1);
    __syncthreads();
    if (t < 64) {
        float s0 = red[t].x + red[t + 64].x + red[t + 128].x + red[t + 192].x;
        float s1 = red[t].y + red[t + 64].y + red[t + 128].y + red[t + 192].y;
        s0 *= os; s1 *= os;
        float hn = s1 / (s0 + 1e-8f);
        float v0 = ti, v1 = s0, v2 = hn;
        #pragma unroll
        for (int k = 0; k < 8; ++k) {
            float z = v0 * mlp_w[k] + v1 * mlp_w[8 + k] + v2 * mlp_w[16 + k] + mlp_b[k];
            float sg = 1.f / (1.f + __expf(-z));
            act0[((size_t)b * 8 + k) * NT_ + i] = sg;
        }
    }
}

// ---------------- fused conv chain ----------------
template <int CI, int CO, int NPIN, int NPOUT, int OUT_OFF, bool TO_GLOBAL>
__device__ inline void conv_layer(const float* __restrict__ wl,  // LDS, [CO*CI][8] padded
                                  const float* __restrict__ bl,  // global bias [CO]
                                  const float* in,               // LDS [CI][NPIN]
                                  float* out,                    // LDS [CO][NPOUT] or global f
                                  int t, int o0, int b) {
    constexpr int PB = NPOUT / 4;
    for (int u = t; u < CO * PB; u += 256) {
        int co = u / PB;
        int p = (u - co * PB) * 4;
        float bias = bl[co];
        float acc0 = bias, acc1 = bias, acc2 = bias, acc3 = bias;
        #pragma unroll
        for (int ci = 0; ci < CI; ++ci) {
            const float* ip = in + ci * NPIN + p;
            float4 ia = *(const float4*)ip;
            float4 ib = *(const float4*)(ip + 4);
            const float* wp = wl + (co * CI + ci) * 8;
            float4 wa = *(const float4*)wp;
            float w4v = wp[4];
            float w0 = ia.x, w1_ = ia.y, w2_ = ia.z, w3_ = ia.w;
            float w4w = ib.x, w5 = ib.y, w6 = ib.z, w7 = ib.w;
            acc0 += w0 * wa.x + w1_ * wa.y + w2_ * wa.z + w3_ * wa.w + w4w * w4v;
            acc1 += w1_ * wa.x + w2_ * wa.y + w3_ * wa.z + w4w * wa.w + w5 * w4v;
            acc2 += w2_ * wa.x + w3_ * wa.y + w4w * wa.z + w5 * wa.w + w6 * w4v;
            acc3 += w3_ * wa.x + w4w * wa.y + w5 * wa.z + w6 * wa.w + w7 * w4v;
        }
        if (!TO_GLOBAL) {
            int gp = o0 + OUT_OFF + p;
            float* op = out + co * NPOUT + p;
            op[0] = ((unsigned)(gp + 0) < (unsigned)NT_) ? fmaxf(acc0, 0.f) : 0.f;
            op[1] = ((unsigned)(gp + 1) < (unsigned)NT_) ? fmaxf(acc1, 0.f) : 0.f;
            op[2] = ((unsigned)(gp + 2) < (unsigned)NT_) ? fmaxf(acc2, 0.f) : 0.f;
            op[3] = ((unsigned)(gp + 3) < (unsigned)NT_) ? fmaxf(acc3, 0.f) : 0.f;
        } else {
            int i = o0 + p;
            float* fp = out + ((size_t)b * NT_ + i) * 8 + co;
            fp[0]  = fmaxf(acc0, 0.f);
            fp[8]  = fmaxf(acc1, 0.f);
            fp[16] = fmaxf(acc2, 0.f);
            fp[24] = fmaxf(acc3, 0.f);
        }
    }
}

__global__ __launch_bounds__(256) void k_conv(const float* __restrict__ w1, const float* __restrict__ b1,
                                              const float* __restrict__ w2, const float* __restrict__ b2,
                                              const float* __restrict__ w3, const float* __restrict__ b3,
                                              const float* __restrict__ w4, const float* __restrict__ b4,
                                              const float* __restrict__ act0, float* __restrict__ f) {
    __shared__ float in0[8 * 80];
    __shared__ float bufA[16 * 76];
    __shared__ float bufB[32 * 72];
    __shared__ float bufC[16 * 68];
    __shared__ float wl1[16 * 8 * 8];
    __shared__ float wl2[32 * 16 * 8];
    __shared__ float wl3[16 * 32 * 8];
    __shared__ float wl4[8 * 16 * 8];

    int t = threadIdx.x;
    int b = blockIdx.y;
    int o0 = blockIdx.x * 64;

    // stage weights (pad 5 -> 8 for aligned float4 reads)
    for (int idx = t; idx < 16 * 8 * 5; idx += 256) { int a = idx / 5, k = idx - a * 5; wl1[a * 8 + k] = w1[idx]; }
    for (int idx = t; idx < 32 * 16 * 5; idx += 256) { int a = idx / 5, k = idx - a * 5; wl2[a * 8 + k] = w2[idx]; }
    for (int idx = t; idx < 16 * 32 * 5; idx += 256) { int a = idx / 5, k = idx - a * 5; wl3[a * 8 + k] = w3[idx]; }
    for (int idx = t; idx < 8 * 16 * 5; idx += 256) { int a = idx / 5, k = idx - a * 5; wl4[a * 8 + k] = w4[idx]; }
    // stage input tile with halo 8
    for (int idx = t; idx < 8 * 80; idx += 256) {
        int ci = idx / 80, p = idx - ci * 80;
        int gp = o0 - 8 + p;
        in0[ci * 80 + p] = ((unsigned)gp < (unsigned)NT_) ? act0[((size_t)b * 8 + ci) * NT_ + gp] : 0.f;
    }
    __syncthreads();
    conv_layer<8, 16, 80, 76, -6, false>(wl1, b1, in0, bufA, t, o0, b);
    __syncthreads();
    conv_layer<16, 32, 76, 72, -4, false>(wl2, b2, bufA, bufB, t, o0, b);
    __syncthreads();
    conv_layer<32, 16, 72, 68, -2, false>(wl3, b3, bufB, bufC, t, o0, b);
    __syncthreads();
    conv_layer<16, 8, 68, 64, 0, true>(wl4, b4, bufC, f, t, o0, b);
}

// ---------------- kernel 4: Krho @ f (truncated), heads, var diag + zero-fill ----------------
__global__ __launch_bounds__(256) void k_stageC(const float* __restrict__ xt,
                                                const float* __restrict__ rho_ls,
                                                const float* __restrict__ rho_os,
                                                const float* __restrict__ mean_w,
                                                const float* __restrict__ mean_b,
                                                const float* __restrict__ var_w,
                                                const float* __restrict__ var_b,
                                                const float* __restrict__ ws,
                                                const float* __restrict__ f,
                                                float* __restrict__ out) {
    __shared__ float vbuf[16];
    int t = threadIdx.x;
    int lane = t & 63, w = t >> 6;
    int b = blockIdx.y;
    int r0 = blockIdx.x * 16;

    float lower = ws[0], step = ws[1];
    float ls = rho_ls[0], os = rho_os[0];
    float nh = -0.5f / (ls * ls);
    float R = ls * 5.68f;  // exp(-16.1) ~ 1e-7 cutoff; abs tol is 0.245
    float inv_step = 1.0f / step;

    for (int rr = 0; rr < 4; ++rr) {
        int rl = rr * 4 + w;
        int r = r0 + rl;
        float xv = xt[(size_t)b * T_ + r];
        int ilo = (int)ceilf((xv - R - lower) * inv_step);
        int ihi = (int)floorf((xv + R - lower) * inv_step);
        ilo = max(ilo, 0);
        ihi = min(ihi, NT_ - 1);
        float a0 = 0, a1 = 0, a2 = 0, a3 = 0, a4 = 0, a5 = 0, a6 = 0, a7 = 0;
        for (int i = ilo + lane; i <= ihi; i += 64) {
            float tiv = lower + step * (float)i;
            float d = xv - tiv;
            float e = __expf(nh * d * d);
            const float4* fp = (const float4*)(f + ((size_t)b * NT_ + i) * 8);
            float4 fa = fp[0], fb = fp[1];
            a0 += e * fa.x; a1 += e * fa.y; a2 += e * fa.z; a3 += e * fa.w;
            a4 += e * fb.x; a5 += e * fb.y; a6 += e * fb.z; a7 += e * fb.w;
        }
        #pragma unroll
        for (int off = 32; off > 0; off >>= 1) {
            a0 += __shfl_xor(a0, off, 64);
            a1 += __shfl_xor(a1, off, 64);
            a2 += __shfl_xor(a2, off, 64);
            a3 += __shfl_xor(a3, off, 64);
            a4 += __shfl_xor(a4, off, 64);
            a5 += __shfl_xor(a5, off, 64);
            a6 += __shfl_xor(a6, off, 64);
            a7 += __shfl_xor(a7, off, 64);
        }
        if (lane == 0) {
            a0 *= os; a1 *= os; a2 *= os; a3 *= os;
            a4 *= os; a5 *= os; a6 *= os; a7 *= os;
            float m = a0 * mean_w[0] + a1 * mean_w[1] + a2 * mean_w[2] + a3 * mean_w[3] +
                      a4 * mean_w[4] + a5 * mean_w[5] + a6 * mean_w[6] + a7 * mean_w[7] + mean_b[0];
            float x = a0 * var_w[0] + a1 * var_w[1] + a2 * var_w[2] + a3 * var_w[3] +
                      a4 * var_w[4] + a5 * var_w[5] + a6 * var_w[6] + a7 * var_w[7] + var_b[0];
            float v = fmaxf(x, 0.f) + log1pf(__expf(-fabsf(x)));  // stable softplus
            out[(size_t)b * T_ + r] = m;
            vbuf[rl] = v;
        }
    }
    __syncthreads();

    float* varout = out + (size_t)B_ * T_;
    for (int row = 0; row < 16; ++row) {
        int r = r0 + row;
        float v = vbuf[row];
        float* base = varout + ((size_t)b * T_ + r) * T_;
        #pragma unroll
        for (int half = 0; half < 2; ++half) {
            int j0 = t * 4 + half * 1024;
            v4 val;
            val.x = (j0 == r) ? v : 0.f;
            val.y = (j0 + 1 == r) ? v : 0.f;
            val.z = (j0 + 2 == r) ? v : 0.f;
            val.w = (j0 + 3 == r) ? v : 0.f;
            __builtin_nontemporal_store(val, (v4*)(base + j0));
        }
    }
}

extern "C" void kernel_launch(void* const* d_in, const int* in_sizes, int n_in,
                              void* d_out, int out_size, void* d_ws, size_t ws_size,
                              hipStream_t stream) {
    const float* xc = (const float*)d_in[0];
    const float* yc = (const float*)d_in[1];
    const float* xt = (const float*)d_in[2];
    const float* psi_ls = (const float*)d_in[4];
    const float* psi_os = (const float*)d_in[5];
    const float* rho_ls = (const float*)d_in[6];
    const float* rho_os = (const float*)d_in[7];
    const float* mlp_w = (const float*)d_in[8];
    const float* mlp_b = (const float*)d_in[9];
    const float* w1 = (const float*)d_in[10];
    const float* b1 = (const float*)d_in[11];
    const float* w2 = (const float*)d_in[12];
    const float* b2 = (const float*)d_in[13];
    const float* w3 = (const float*)d_in[14];
    const float* b3 = (const float*)d_in[15];
    const float* w4 = (const float*)d_in[16];
    const float* b4 = (const float*)d_in[17];
    const float* mean_w = (const float*)d_in[18];
    const float* mean_b = (const float*)d_in[19];
    const float* var_w = (const float*)d_in[20];
    const float* var_b = (const float*)d_in[21];

    float* ws = (float*)d_ws;
    float* act0 = ws + 64;                       // (B,8,NT)  512 KB
    float* f = act0 + (size_t)B_ * 8 * NT_;      // (B,NT,8)  512 KB
    float* out = (float*)d_out;                  // mean (B,T) then var (B,T,T)

    k_minmax<<<1, 256, 0, stream>>>(xc, xt, ws);
    k_stageA<<<dim3(NT_ / 64, B_), 256, 0, stream>>>(xc, yc, psi_ls, psi_os, mlp_w, mlp_b, ws, act0);
    k_conv<<<dim3(NT_ / 64, B_), 256, 0, stream>>>(w1, b1, w2, b2, w3, b3, w4, b4, act0, f);
    k_stageC<<<dim3(T_ / 16, B_), 256, 0, stream>>>(xt, rho_ls, rho_os, mean_w, mean_b,
                                                    var_w, var_b, ws, f, out);
}

// Round 2
// 58.247 us; speedup vs baseline: 1.4161x; 1.4161x over previous
//
#include <hip/hip_runtime.h>

#define B_ 8
#define C_ 2048
#define T_ 2048
#define NT_ 2048

typedef float v4 __attribute__((ext_vector_type(4)));

// ---------------- kernel 1: global min/max over xc and xt ----------------
__global__ __launch_bounds__(1024) void k_minmax(const float* __restrict__ xc,
                                                 const float* __restrict__ xt,
                                                 float* __restrict__ ws) {
    __shared__ float slo[1024], shi[1024];
    int t = threadIdx.x;
    float lo = 1e30f, hi = -1e30f;
    const float4* x4 = (const float4*)xc;
    const float4* t4 = (const float4*)xt;
    for (int idx = t; idx < B_ * C_ / 4; idx += 1024) {
        float4 a = x4[idx];
        lo = fminf(lo, fminf(fminf(a.x, a.y), fminf(a.z, a.w)));
        hi = fmaxf(hi, fmaxf(fmaxf(a.x, a.y), fmaxf(a.z, a.w)));
        float4 c = t4[idx];
        lo = fminf(lo, fminf(fminf(c.x, c.y), fminf(c.z, c.w)));
        hi = fmaxf(hi, fmaxf(fmaxf(c.x, c.y), fmaxf(c.z, c.w)));
    }
    slo[t] = lo; shi[t] = hi;
    __syncthreads();
    for (int s = 512; s > 0; s >>= 1) {
        if (t < s) {
            slo[t] = fminf(slo[t], slo[t + s]);
            shi[t] = fmaxf(shi[t], shi[t + s]);
        }
        __syncthreads();
    }
    if (t == 0) {
        float lower = slo[0], upper = shi[0];
        ws[0] = lower;
        ws[1] = (upper - lower) * (1.0f / 2047.0f);  // linspace step
    }
}

// ---------------- fused conv layer (LDS -> LDS) ----------------
template <int CI, int CO, int NPIN, int NPOUT, int OUT_OFF, int NTH>
__device__ inline void conv_layer(const float* __restrict__ wl,  // LDS, [CO*CI][8] padded
                                  const float* __restrict__ bl,  // global bias [CO]
                                  const float* in,               // LDS [CI][NPIN]
                                  float* out,                    // LDS [CO][NPOUT]
                                  int t, int o0) {
    constexpr int PB = NPOUT / 4;
    for (int u = t; u < CO * PB; u += NTH) {
        int co = u / PB;
        int p = (u - co * PB) * 4;
        float bias = bl[co];
        float acc0 = bias, acc1 = bias, acc2 = bias, acc3 = bias;
        #pragma unroll
        for (int ci = 0; ci < CI; ++ci) {
            const float* ip = in + ci * NPIN + p;
            float4 ia = *(const float4*)ip;
            float4 ib = *(const float4*)(ip + 4);
            const float* wp = wl + (co * CI + ci) * 8;
            float4 wa = *(const float4*)wp;
            float w4v = wp[4];
            float e0 = ia.x, e1 = ia.y, e2 = ia.z, e3 = ia.w;
            float e4 = ib.x, e5 = ib.y, e6 = ib.z, e7 = ib.w;
            acc0 += e0 * wa.x + e1 * wa.y + e2 * wa.z + e3 * wa.w + e4 * w4v;
            acc1 += e1 * wa.x + e2 * wa.y + e3 * wa.z + e4 * wa.w + e5 * w4v;
            acc2 += e2 * wa.x + e3 * wa.y + e4 * wa.z + e5 * wa.w + e6 * w4v;
            acc3 += e3 * wa.x + e4 * wa.y + e5 * wa.z + e6 * wa.w + e7 * w4v;
        }
        int gp = o0 + OUT_OFF + p;
        float* op = out + co * NPOUT + p;
        op[0] = ((unsigned)(gp + 0) < (unsigned)NT_) ? fmaxf(acc0, 0.f) : 0.f;
        op[1] = ((unsigned)(gp + 1) < (unsigned)NT_) ? fmaxf(acc1, 0.f) : 0.f;
        op[2] = ((unsigned)(gp + 2) < (unsigned)NT_) ? fmaxf(acc2, 0.f) : 0.f;
        op[3] = ((unsigned)(gp + 3) < (unsigned)NT_) ? fmaxf(acc3, 0.f) : 0.f;
    }
}

// ---------------- kernel 2: SetConv + MLP + conv chain -> (fm,fv) per grid point ----------------
__global__ __launch_bounds__(512) void k_stageAB(const float* __restrict__ xc,
                                                 const float* __restrict__ yc,
                                                 const float* __restrict__ psi_ls,
                                                 const float* __restrict__ psi_os,
                                                 const float* __restrict__ mlp_w,
                                                 const float* __restrict__ mlp_b,
                                                 const float* __restrict__ w1, const float* __restrict__ b1,
                                                 const float* __restrict__ w2, const float* __restrict__ b2,
                                                 const float* __restrict__ w3, const float* __restrict__ b3,
                                                 const float* __restrict__ w4, const float* __restrict__ b4,
                                                 const float* __restrict__ mean_w,
                                                 const float* __restrict__ var_w,
                                                 const float* __restrict__ ws,
                                                 float2* __restrict__ g2out) {
    __shared__ float2 cxy[C_];
    __shared__ float2 red[512];
    __shared__ float2 red2[512];
    __shared__ float in0[8 * 80];
    __shared__ float bufA[16 * 76];
    __shared__ float bufB[32 * 72];
    __shared__ float bufC[16 * 68];
    __shared__ float bufD[8 * 64];
    __shared__ float wl1[16 * 8 * 8];
    __shared__ float wl2[32 * 16 * 8];
    __shared__ float wl3[16 * 32 * 8];
    __shared__ float wl4[8 * 16 * 8];

    int t = threadIdx.x;
    int b = blockIdx.y;
    int o0 = blockIdx.x * 64;

    const float* xcb = xc + b * C_;
    const float* ycb = yc + b * C_;
    for (int j = t; j < C_; j += 512) cxy[j] = make_float2(xcb[j], ycb[j]);
    for (int idx = t; idx < 16 * 8 * 5; idx += 512) { int a = idx / 5, k = idx - a * 5; wl1[a * 8 + k] = w1[idx]; }
    for (int idx = t; idx < 32 * 16 * 5; idx += 512) { int a = idx / 5, k = idx - a * 5; wl2[a * 8 + k] = w2[idx]; }
    for (int idx = t; idx < 16 * 32 * 5; idx += 512) { int a = idx / 5, k = idx - a * 5; wl3[a * 8 + k] = w3[idx]; }
    for (int idx = t; idx < 8 * 16 * 5; idx += 512) { int a = idx / 5, k = idx - a * 5; wl4[a * 8 + k] = w4[idx]; }
    __syncthreads();

    float lower = ws[0], step = ws[1];
    float ls = psi_ls[0], os = psi_os[0];
    float nh = -0.5f / (ls * ls);

    // round 1: 64 main points, 8 groups x 256 ctx each (g wave-uniform -> LDS broadcast)
    {
        int il = t & 63, g = t >> 6;
        float ti = lower + step * (float)(o0 + il);
        float h0 = 0.f, h1 = 0.f;
        int jb = g * 256;
        #pragma unroll 4
        for (int jj = 0; jj < 256; ++jj) {
            float2 p = cxy[jb + jj];
            float d = ti - p.x;
            float e = __expf(nh * d * d);
            h0 += e;
            h1 += e * p.y;
        }
        red[t] = make_float2(h0, h1);
    }
    // round 2: 16 halo points, 32 groups x 64 ctx each (stagger start to dodge bank conflicts)
    {
        int idx = t & 15, g = t >> 4;
        int p = (idx < 8) ? idx : 64 + idx;      // in0 position
        int gp = o0 - 8 + p;                     // global grid index (may be out of range)
        float ti = lower + step * (float)gp;
        float h0 = 0.f, h1 = 0.f;
        int jb = g * 64;
        int rot = (g & 3) << 2;
        #pragma unroll 4
        for (int jj = 0; jj < 64; ++jj) {
            float2 p2 = cxy[jb + ((jj + rot) & 63)];
            float d = ti - p2.x;
            float e = __expf(nh * d * d);
            h0 += e;
            h1 += e * p2.y;
        }
        red2[t] = make_float2(h0, h1);
    }
    __syncthreads();

    // concurrent finalize: t<64 -> main points; t in [64,80) -> halo points
    if (t < 64) {
        float s0 = 0.f, s1 = 0.f;
        #pragma unroll
        for (int k = 0; k < 8; ++k) { float2 r = red[t + 64 * k]; s0 += r.x; s1 += r.y; }
        s0 *= os; s1 *= os;
        float hn = s1 / (s0 + 1e-8f);
        float tiv = lower + step * (float)(o0 + t);
        #pragma unroll
        for (int k = 0; k < 8; ++k) {
            float z = tiv * mlp_w[k] + s0 * mlp_w[8 + k] + hn * mlp_w[16 + k] + mlp_b[k];
            in0[k * 80 + 8 + t] = 1.f / (1.f + __expf(-z));
        }
    } else if (t < 80) {
        int idx = t - 64;
        float s0 = 0.f, s1 = 0.f;
        #pragma unroll
        for (int k = 0; k < 32; ++k) { float2 r = red2[idx + 16 * k]; s0 += r.x; s1 += r.y; }
        int p = (idx < 8) ? idx : 64 + idx;
        int gp = o0 - 8 + p;
        if ((unsigned)gp < (unsigned)NT_) {
            s0 *= os; s1 *= os;
            float hn = s1 / (s0 + 1e-8f);
            float tiv = lower + step * (float)gp;
            #pragma unroll
            for (int k = 0; k < 8; ++k) {
                float z = tiv * mlp_w[k] + s0 * mlp_w[8 + k] + hn * mlp_w[16 + k] + mlp_b[k];
                in0[k * 80 + p] = 1.f / (1.f + __expf(-z));
            }
        } else {
            #pragma unroll
            for (int k = 0; k < 8; ++k) in0[k * 80 + p] = 0.f;
        }
    }
    __syncthreads();

    conv_layer<8, 16, 80, 76, -6, 512>(wl1, b1, in0, bufA, t, o0);
    __syncthreads();
    conv_layer<16, 32, 76, 72, -4, 512>(wl2, b2, bufA, bufB, t, o0);
    __syncthreads();
    conv_layer<32, 16, 72, 68, -2, 512>(wl3, b3, bufB, bufC, t, o0);
    __syncthreads();
    conv_layer<16, 8, 68, 64, 0, 512>(wl4, b4, bufC, bufD, t, o0);
    __syncthreads();

    // project 8 channels onto (mean_w, var_w): (Krho@f)@w == Krho@(f@w)
    if (t < 64) {
        float fm = 0.f, fv = 0.f;
        #pragma unroll
        for (int c = 0; c < 8; ++c) {
            float x = bufD[c * 64 + t];
            fm += x * mean_w[c];
            fv += x * var_w[c];
        }
        g2out[(size_t)b * NT_ + o0 + t] = make_float2(fm, fv);
    }
}

// ---------------- kernel 3: truncated Krho reduce + heads + var diag fill ----------------
__global__ __launch_bounds__(256) void k_stageC(const float* __restrict__ xt,
                                                const float* __restrict__ rho_ls,
                                                const float* __restrict__ rho_os,
                                                const float* __restrict__ mean_b,
                                                const float* __restrict__ var_b,
                                                const float* __restrict__ ws,
                                                const float2* __restrict__ g2,
                                                float* __restrict__ out) {
    int t = threadIdx.x;
    int lane = t & 63, w = t >> 6;
    int b = blockIdx.y;
    int r0 = blockIdx.x * 16;

    float lower = ws[0], step = ws[1];
    float ls = rho_ls[0], os = rho_os[0];
    float nh = -0.5f / (ls * ls);
    float R = ls * 5.68f;  // exp(-16.1) ~ 1e-7 cutoff; abs tol is 0.245
    float inv_step = 1.0f / step;
    float mb = mean_b[0], vb = var_b[0];

    const float2* gb = g2 + (size_t)b * NT_;
    float* varout = out + (size_t)B_ * T_;

    for (int rr = 0; rr < 4; ++rr) {
        int r = r0 + w * 4 + rr;
        float xv = xt[(size_t)b * T_ + r];
        int ilo = max((int)ceilf((xv - R - lower) * inv_step), 0);
        int ihi = min((int)floorf((xv + R - lower) * inv_step), NT_ - 1);
        float mp = 0.f, vp = 0.f;
        for (int i = ilo + lane; i <= ihi; i += 64) {
            float d = xv - (lower + step * (float)i);
            float e = __expf(nh * d * d);
            float2 gg = gb[i];
            mp += e * gg.x;
            vp += e * gg.y;
        }
        #pragma unroll
        for (int off = 32; off > 0; off >>= 1) {
            mp += __shfl_xor(mp, off, 64);
            vp += __shfl_xor(vp, off, 64);
        }
        float m = os * mp + mb;
        float x = os * vp + vb;
        float v = fmaxf(x, 0.f) + log1pf(__expf(-fabsf(x)));  // stable softplus
        if (lane == 0) out[(size_t)b * T_ + r] = m;
        // fill this var row: 2048 floats, diag at column r
        float* base = varout + ((size_t)b * T_ + r) * T_;
        #pragma unroll
        for (int seg = 0; seg < 8; ++seg) {
            int j0 = seg * 256 + lane * 4;
            v4 val;
            val.x = (j0 == r) ? v : 0.f;
            val.y = (j0 + 1 == r) ? v : 0.f;
            val.z = (j0 + 2 == r) ? v : 0.f;
            val.w = (j0 + 3 == r) ? v : 0.f;
            __builtin_nontemporal_store(val, (v4*)(base + j0));
        }
    }
}

extern "C" void kernel_launch(void* const* d_in, const int* in_sizes, int n_in,
                              void* d_out, int out_size, void* d_ws, size_t ws_size,
                              hipStream_t stream) {
    const float* xc = (const float*)d_in[0];
    const float* yc = (const float*)d_in[1];
    const float* xt = (const float*)d_in[2];
    const float* psi_ls = (const float*)d_in[4];
    const float* psi_os = (const float*)d_in[5];
    const float* rho_ls = (const float*)d_in[6];
    const float* rho_os = (const float*)d_in[7];
    const float* mlp_w = (const float*)d_in[8];
    const float* mlp_b = (const float*)d_in[9];
    const float* w1 = (const float*)d_in[10];
    const float* b1 = (const float*)d_in[11];
    const float* w2 = (const float*)d_in[12];
    const float* b2 = (const float*)d_in[13];
    const float* w3 = (const float*)d_in[14];
    const float* b3 = (const float*)d_in[15];
    const float* w4 = (const float*)d_in[16];
    const float* b4 = (const float*)d_in[17];
    const float* mean_w = (const float*)d_in[18];
    const float* mean_b = (const float*)d_in[19];
    const float* var_w = (const float*)d_in[20];
    const float* var_b = (const float*)d_in[21];

    float* ws = (float*)d_ws;
    float2* g2 = (float2*)(ws + 64);             // (B,NT) x (fm,fv)  128 KB
    float* out = (float*)d_out;                  // mean (B,T) then var (B,T,T)

    k_minmax<<<1, 1024, 0, stream>>>(xc, xt, ws);
    k_stageAB<<<dim3(NT_ / 64, B_), 512, 0, stream>>>(xc, yc, psi_ls, psi_os, mlp_w, mlp_b,
                                                      w1, b1, w2, b2, w3, b3, w4, b4,
                                                      mean_w, var_w, ws, g2);
    k_stageC<<<dim3(T_ / 16, B_), 256, 0, stream>>>(xt, rho_ls, rho_os, mean_b, var_b, ws, g2, out);
}